// Round 1
// baseline (314.390 us; speedup 1.0000x reference)
//
#include <hip/hip_runtime.h>
#include <hip/hip_bf16.h>

typedef __attribute__((ext_vector_type(8))) short bf16x8;
typedef __attribute__((ext_vector_type(4))) short bf16x4;
typedef __attribute__((ext_vector_type(4))) float f32x4;

#define NU 20

__device__ __forceinline__ float b2f(unsigned short u) {
    union { float f; unsigned v; } x; x.v = ((unsigned)u) << 16; return x.f;
}
__device__ __forceinline__ unsigned short f2b(float f) {
    union { float f; unsigned v; } x; x.f = f;
    unsigned r = x.v + 0x7FFF + ((x.v >> 16) & 1);
    return (unsigned short)(r >> 16);
}

// ================= build stage (parallelized: 424 + 4 + 400 + 4 blocks) =========
// L = H^U_0...H^U_19 = I - A B^T (B cols = U rows), R = H^V_19...H^V_0 = I - C D^T
// out = x*s - r.G^T + bias,  r = x.F,  F=[A | S C - A E], G=[S B | D], E=B^T S C

// blocks 0..209: GU pair, 210..419: GV pair, 420..423: sigma/bias chunk
__global__ __launch_bounds__(256) void k_gram(
        const float* __restrict__ U, const float* __restrict__ p,
        const float* __restrict__ V, const float* __restrict__ bias,
        float* __restrict__ GU, float* __restrict__ GV,
        float* __restrict__ s_ws, float* __restrict__ b_ws) {
    const int b = blockIdx.x, T = threadIdx.x;
    if (b >= 420) {
        int t = (b - 420) * 256 + T;
        float pv = p[t];
        s_ws[t] = 0.4f / (1.0f + __expf(-pv)) + 0.6f;
        b_ws[t] = bias[t];
        return;
    }
    const float* M = (b < 210) ? U : V;
    float* Gm = (b < 210) ? GU : GV;
    int i = (b < 210) ? b : b - 210;
    int k = 0;
    while ((k + 1) * (k + 2) / 2 <= i) k++;
    int j = i - k * (k + 1) / 2;
    f32x4 a4 = *(const f32x4*)&M[j * 1024 + T * 4];
    f32x4 b4 = *(const f32x4*)&M[k * 1024 + T * 4];
    float acc = a4[0] * b4[0] + a4[1] * b4[1] + a4[2] * b4[2] + a4[3] * b4[3];
    for (int off = 32; off; off >>= 1) acc += __shfl_down(acc, off, 64);
    __shared__ float part[4];
    if ((T & 63) == 0) part[T >> 6] = acc;
    __syncthreads();
    if (T == 0) {
        float s = part[0] + part[1] + part[2] + part[3];
        Gm[j * 20 + k] = s; Gm[k * 20 + j] = s;
    }
}

// 4 blocks x 256: per-dim WY recurrences; writes A, Csc, Ft rows 0..19 & 40..63, G
__global__ __launch_bounds__(256) void k_recur(
        const float* __restrict__ U, const float* __restrict__ V,
        const float* __restrict__ GUg, const float* __restrict__ GVg,
        const float* __restrict__ s_ws,
        float* __restrict__ A, float* __restrict__ Csc,
        unsigned short* __restrict__ Ft, unsigned short* __restrict__ G) {
    __shared__ float sGU[400], sGV[400];
    const int T = threadIdx.x;
    const int t = blockIdx.x * 256 + T;
    for (int i = T; i < 400; i += 256) { sGU[i] = GUg[i]; sGV[i] = GVg[i]; }
    __syncthreads();
    float sig = s_ws[t];
    float a[NU], c[NU];
    for (int k = 0; k < NU; k++) {
        float w = U[k * 1024 + t];
        for (int j = 0; j < k; j++) w -= a[j] * sGU[j * 20 + k];
        a[k] = (2.0f / sGU[k * 20 + k]) * w;
    }
    for (int k = NU - 1; k >= 0; k--) {
        float w = V[k * 1024 + t];
        for (int j = k + 1; j < NU; j++) w -= c[j] * sGV[j * 20 + k];
        c[k] = (2.0f / sGV[k * 20 + k]) * w;
    }
    for (int k = 0; k < NU; k++) { A[k * 1024 + t] = a[k]; Ft[k * 1024 + t] = f2b(a[k]); }
    for (int b = 0; b < NU; b++) Csc[b * 1024 + t] = sig * c[b];
    for (int k = 2 * NU; k < 64; k++) Ft[k * 1024 + t] = 0;
    for (int k = 0; k < NU; k++) G[t * 64 + k] = f2b(sig * U[k * 1024 + t]);
    for (int k = 0; k < NU; k++) G[t * 64 + NU + k] = f2b(V[k * 1024 + t]);
    for (int k = 2 * NU; k < 64; k++) G[t * 64 + k] = 0;
}

// 400 blocks: E[a][b] = dot(U row a, Csc row b)
__global__ __launch_bounds__(256) void k_e(
        const float* __restrict__ U, const float* __restrict__ Csc,
        float* __restrict__ E) {
    const int aa = blockIdx.x / 20, bb = blockIdx.x % 20;
    const int T = threadIdx.x;
    f32x4 a4 = *(const f32x4*)&U[aa * 1024 + T * 4];
    f32x4 b4 = *(const f32x4*)&Csc[bb * 1024 + T * 4];
    float acc = a4[0] * b4[0] + a4[1] * b4[1] + a4[2] * b4[2] + a4[3] * b4[3];
    for (int off = 32; off; off >>= 1) acc += __shfl_down(acc, off, 64);
    __shared__ float part[4];
    if ((T & 63) == 0) part[T >> 6] = acc;
    __syncthreads();
    if (T == 0) E[aa * 20 + bb] = part[0] + part[1] + part[2] + part[3];
}

// 4 blocks x 256: Ft rows 20..39 = (S C - A E) columns
__global__ __launch_bounds__(256) void k_f2(
        const float* __restrict__ A, const float* __restrict__ Csc,
        const float* __restrict__ Eg, unsigned short* __restrict__ Ft) {
    __shared__ float sE[400];
    const int T = threadIdx.x;
    const int t = blockIdx.x * 256 + T;
    for (int i = T; i < 400; i += 256) sE[i] = Eg[i];
    __syncthreads();
    float av[NU];
    for (int a = 0; a < NU; a++) av[a] = A[a * 1024 + t];
    for (int b = 0; b < NU; b++) {
        float v = Csc[b * 1024 + t];
        for (int a = 0; a < NU; a++) v -= av[a] * sE[a * 20 + b];
        Ft[(NU + b) * 1024 + t] = f2b(v);
    }
}

// ============== fused main, v2: 16-row blocks, grid 2048 =======================
// Phase A: waves split K (256 each), x global->reg->MFMA (no LDS, no barriers).
// LDS reduce of 4 partials -> r(16x64) bf16. Phase B: waves split N (256 cols).
// Only 2 barriers per block; high occupancy to saturate HBM.
__global__ __launch_bounds__(256, 4) void k_main(
        const float* __restrict__ x, const unsigned short* __restrict__ Ft,
        const unsigned short* __restrict__ G, const float* __restrict__ s_ws,
        const float* __restrict__ b_ws, float* __restrict__ out) {
    __shared__ __align__(16) float sA[4][16][64];        // 16 KiB partials
    __shared__ __align__(16) unsigned short rl[16][72];  // r tile, padded

    const int T = threadIdx.x;
    const int wv = T >> 6, lane = T & 63;
    const int mc = lane & 15, quad = lane >> 4;
    const int m0 = blockIdx.x * 16;

    // ---- Phase A: partial r(16x64) over K in [wv*256, wv*256+256) ----
    f32x4 acc1[4];
#pragma unroll
    for (int i = 0; i < 4; i++) acc1[i] = (f32x4){0.f, 0.f, 0.f, 0.f};

    const float* xp = &x[(size_t)(m0 + mc) * 1024 + wv * 256 + quad * 8];
    const unsigned short* fp = &Ft[(size_t)mc * 1024 + wv * 256 + quad * 8];

    // 2-deep x prefetch (HBM ~900cy), 1-deep F prefetch (L2-resident)
    f32x4 xa0 = *(const f32x4*)(xp);
    f32x4 xb0 = *(const f32x4*)(xp + 4);
    f32x4 xa1 = *(const f32x4*)(xp + 32);
    f32x4 xb1 = *(const f32x4*)(xp + 36);
    bf16x8 f0 = *(const bf16x8*)(fp);
    bf16x8 f1 = *(const bf16x8*)(fp + 16384);
    bf16x8 f2 = *(const bf16x8*)(fp + 32768);
    bf16x8 f3 = *(const bf16x8*)(fp + 49152);

#pragma unroll
    for (int ks = 0; ks < 8; ks++) {
        f32x4 xa2, xb2; bf16x8 n0, n1, n2, n3;
        if (ks < 6) {
            const float* xq = xp + (ks + 2) * 32;
            xa2 = *(const f32x4*)(xq);
            xb2 = *(const f32x4*)(xq + 4);
        }
        if (ks < 7) {
            const unsigned short* fq = fp + (ks + 1) * 32;
            n0 = *(const bf16x8*)(fq);
            n1 = *(const bf16x8*)(fq + 16384);
            n2 = *(const bf16x8*)(fq + 32768);
            n3 = *(const bf16x8*)(fq + 49152);
        }
        bf16x8 af;
#pragma unroll
        for (int j = 0; j < 4; j++) {
            af[j]     = (short)f2b(xa0[j]);
            af[j + 4] = (short)f2b(xb0[j]);
        }
        acc1[0] = __builtin_amdgcn_mfma_f32_16x16x32_bf16(af, f0, acc1[0], 0, 0, 0);
        acc1[1] = __builtin_amdgcn_mfma_f32_16x16x32_bf16(af, f1, acc1[1], 0, 0, 0);
        acc1[2] = __builtin_amdgcn_mfma_f32_16x16x32_bf16(af, f2, acc1[2], 0, 0, 0);
        acc1[3] = __builtin_amdgcn_mfma_f32_16x16x32_bf16(af, f3, acc1[3], 0, 0, 0);
        if (ks < 7) {
            xa0 = xa1; xb0 = xb1;
            f0 = n0; f1 = n1; f2 = n2; f3 = n3;
        }
        if (ks < 6) { xa1 = xa2; xb1 = xb2; }
    }

    // partials -> LDS (C-layout: row = quad*4+rg, col = nt*16+mc)
#pragma unroll
    for (int nt = 0; nt < 4; nt++)
#pragma unroll
        for (int rg = 0; rg < 4; rg++)
            sA[wv][quad * 4 + rg][nt * 16 + mc] = acc1[nt][rg];
    __syncthreads();

    // reduce 4 partials -> r tile in rl (bf16); 256 threads x 4 elems
    {
        const int row = T >> 4, c0 = (T & 15) * 4;
        f32x4 v = *(const f32x4*)&sA[0][row][c0];
#pragma unroll
        for (int w = 1; w < 4; w++) {
            f32x4 u = *(const f32x4*)&sA[w][row][c0];
            v[0] += u[0]; v[1] += u[1]; v[2] += u[2]; v[3] += u[3];
        }
        bf16x4 rv;
#pragma unroll
        for (int j = 0; j < 4; j++) rv[j] = (short)f2b(v[j]);
        *(bf16x4*)&rl[row][c0] = rv;
    }
    __syncthreads();

    // ---- Phase B: out cols [wv*256, wv*256+256), 16 n-frags of 16 ----
    bf16x8 pa0 = *(const bf16x8*)&rl[mc][quad * 8];
    bf16x8 pa1 = *(const bf16x8*)&rl[mc][32 + quad * 8];
    const int C0 = wv * 256;

#pragma unroll 2
    for (int nf = 0; nf < 16; nf++) {
        const int col = C0 + nf * 16 + mc;
        const unsigned short* gp = &G[(size_t)col * 64 + quad * 8];
        bf16x8 g0 = *(const bf16x8*)(gp);
        bf16x8 g1 = *(const bf16x8*)(gp + 32);
        f32x4 a = (f32x4){0.f, 0.f, 0.f, 0.f};
        a = __builtin_amdgcn_mfma_f32_16x16x32_bf16(pa0, g0, a, 0, 0, 0);
        a = __builtin_amdgcn_mfma_f32_16x16x32_bf16(pa1, g1, a, 0, 0, 0);
        const float sv = s_ws[col], bv = b_ws[col];
        size_t base = (size_t)(m0 + quad * 4) * 1024 + col;
        out[base]        = x[base]        * sv - a[0] + bv;
        out[base + 1024] = x[base + 1024] * sv - a[1] + bv;
        out[base + 2048] = x[base + 2048] * sv - a[2] + bv;
        out[base + 3072] = x[base + 3072] * sv - a[3] + bv;
    }
}

extern "C" void kernel_launch(void* const* d_in, const int* in_sizes, int n_in,
                              void* d_out, int out_size, void* d_ws, size_t ws_size,
                              hipStream_t stream) {
    const float* x    = (const float*)d_in[0];
    const float* U    = (const float*)d_in[1];
    const float* p    = (const float*)d_in[2];
    const float* V    = (const float*)d_in[3];
    const float* bias = (const float*)d_in[4];

    char* ws = (char*)d_ws;
    unsigned short* Ft = (unsigned short*)ws;               // 131072 B
    unsigned short* G  = (unsigned short*)(ws + 131072);    // 131072 B
    float* s_ws        = (float*)(ws + 262144);             // 4096 B
    float* b_ws        = (float*)(ws + 266240);             // 4096 B
    float* GU          = (float*)(ws + 270336);             // 4096 B
    float* GV          = (float*)(ws + 274432);             // 4096 B
    float* A           = (float*)(ws + 278528);             // 81920 B
    float* Csc         = (float*)(ws + 360448);             // 81920 B
    float* E           = (float*)(ws + 442368);             // 4096 B
    float* out = (float*)d_out;

    hipLaunchKernelGGL(k_gram,  dim3(424),  dim3(256), 0, stream, U, p, V, bias, GU, GV, s_ws, b_ws);
    hipLaunchKernelGGL(k_recur, dim3(4),    dim3(256), 0, stream, U, V, GU, GV, s_ws, A, Csc, Ft, G);
    hipLaunchKernelGGL(k_e,     dim3(400),  dim3(256), 0, stream, U, Csc, E);
    hipLaunchKernelGGL(k_f2,    dim3(4),    dim3(256), 0, stream, A, Csc, E, Ft);
    hipLaunchKernelGGL(k_main,  dim3(2048), dim3(256), 0, stream, x, Ft, G, s_ws, b_ws, out);
}

// Round 2
// 306.173 us; speedup vs baseline: 1.0268x; 1.0268x over previous
//
#include <hip/hip_runtime.h>
#include <hip/hip_bf16.h>

typedef __attribute__((ext_vector_type(8))) short bf16x8;
typedef __attribute__((ext_vector_type(4))) short bf16x4;
typedef __attribute__((ext_vector_type(4))) float f32x4;

#define NU 20

__device__ __forceinline__ float b2f(unsigned short u) {
    union { float f; unsigned v; } x; x.v = ((unsigned)u) << 16; return x.f;
}
__device__ __forceinline__ unsigned short f2b(float f) {
    union { float f; unsigned v; } x; x.f = f;
    unsigned r = x.v + 0x7FFF + ((x.v >> 16) & 1);
    return (unsigned short)(r >> 16);
}

__device__ __forceinline__ void gload_lds16(const void* g, void* l) {
    __builtin_amdgcn_global_load_lds(
        (const __attribute__((address_space(1))) void*)g,
        (__attribute__((address_space(3))) void*)l, 16, 0, 0);
}

// ================= build stage (parallelized: 424 + 4 + 400 + 4 blocks) =========
// L = H^U_0...H^U_19 = I - A B^T (B cols = U rows), R = H^V_19...H^V_0 = I - C D^T
// out = x*s - r.G^T + bias,  r = x.F,  F=[A | S C - A E], G=[S B | D], E=B^T S C

// blocks 0..209: GU pair, 210..419: GV pair, 420..423: sigma/bias chunk
__global__ __launch_bounds__(256) void k_gram(
        const float* __restrict__ U, const float* __restrict__ p,
        const float* __restrict__ V, const float* __restrict__ bias,
        float* __restrict__ GU, float* __restrict__ GV,
        float* __restrict__ s_ws, float* __restrict__ b_ws) {
    const int b = blockIdx.x, T = threadIdx.x;
    if (b >= 420) {
        int t = (b - 420) * 256 + T;
        float pv = p[t];
        s_ws[t] = 0.4f / (1.0f + __expf(-pv)) + 0.6f;
        b_ws[t] = bias[t];
        return;
    }
    const float* M = (b < 210) ? U : V;
    float* Gm = (b < 210) ? GU : GV;
    int i = (b < 210) ? b : b - 210;
    int k = 0;
    while ((k + 1) * (k + 2) / 2 <= i) k++;
    int j = i - k * (k + 1) / 2;
    f32x4 a4 = *(const f32x4*)&M[j * 1024 + T * 4];
    f32x4 b4 = *(const f32x4*)&M[k * 1024 + T * 4];
    float acc = a4[0] * b4[0] + a4[1] * b4[1] + a4[2] * b4[2] + a4[3] * b4[3];
    for (int off = 32; off; off >>= 1) acc += __shfl_down(acc, off, 64);
    __shared__ float part[4];
    if ((T & 63) == 0) part[T >> 6] = acc;
    __syncthreads();
    if (T == 0) {
        float s = part[0] + part[1] + part[2] + part[3];
        Gm[j * 20 + k] = s; Gm[k * 20 + j] = s;
    }
}

// 4 blocks x 256: per-dim WY recurrences; writes A, Csc, Ft rows 0..19 & 40..63, G
__global__ __launch_bounds__(256) void k_recur(
        const float* __restrict__ U, const float* __restrict__ V,
        const float* __restrict__ GUg, const float* __restrict__ GVg,
        const float* __restrict__ s_ws,
        float* __restrict__ A, float* __restrict__ Csc,
        unsigned short* __restrict__ Ft, unsigned short* __restrict__ G) {
    __shared__ float sGU[400], sGV[400];
    const int T = threadIdx.x;
    const int t = blockIdx.x * 256 + T;
    for (int i = T; i < 400; i += 256) { sGU[i] = GUg[i]; sGV[i] = GVg[i]; }
    __syncthreads();
    float sig = s_ws[t];
    float a[NU], c[NU];
    for (int k = 0; k < NU; k++) {
        float w = U[k * 1024 + t];
        for (int j = 0; j < k; j++) w -= a[j] * sGU[j * 20 + k];
        a[k] = (2.0f / sGU[k * 20 + k]) * w;
    }
    for (int k = NU - 1; k >= 0; k--) {
        float w = V[k * 1024 + t];
        for (int j = k + 1; j < NU; j++) w -= c[j] * sGV[j * 20 + k];
        c[k] = (2.0f / sGV[k * 20 + k]) * w;
    }
    for (int k = 0; k < NU; k++) { A[k * 1024 + t] = a[k]; Ft[k * 1024 + t] = f2b(a[k]); }
    for (int b = 0; b < NU; b++) Csc[b * 1024 + t] = sig * c[b];
    for (int k = 2 * NU; k < 64; k++) Ft[k * 1024 + t] = 0;
    for (int k = 0; k < NU; k++) G[t * 64 + k] = f2b(sig * U[k * 1024 + t]);
    for (int k = 0; k < NU; k++) G[t * 64 + NU + k] = f2b(V[k * 1024 + t]);
    for (int k = 2 * NU; k < 64; k++) G[t * 64 + k] = 0;
}

// 400 blocks: E[a][b] = dot(U row a, Csc row b)
__global__ __launch_bounds__(256) void k_e(
        const float* __restrict__ U, const float* __restrict__ Csc,
        float* __restrict__ E) {
    const int aa = blockIdx.x / 20, bb = blockIdx.x % 20;
    const int T = threadIdx.x;
    f32x4 a4 = *(const f32x4*)&U[aa * 1024 + T * 4];
    f32x4 b4 = *(const f32x4*)&Csc[bb * 1024 + T * 4];
    float acc = a4[0] * b4[0] + a4[1] * b4[1] + a4[2] * b4[2] + a4[3] * b4[3];
    for (int off = 32; off; off >>= 1) acc += __shfl_down(acc, off, 64);
    __shared__ float part[4];
    if ((T & 63) == 0) part[T >> 6] = acc;
    __syncthreads();
    if (T == 0) E[aa * 20 + bb] = part[0] + part[1] + part[2] + part[3];
}

// 4 blocks x 256: Ft rows 20..39 = (S C - A E) columns
__global__ __launch_bounds__(256) void k_f2(
        const float* __restrict__ A, const float* __restrict__ Csc,
        const float* __restrict__ Eg, unsigned short* __restrict__ Ft) {
    __shared__ float sE[400];
    const int T = threadIdx.x;
    const int t = blockIdx.x * 256 + T;
    for (int i = T; i < 400; i += 256) sE[i] = Eg[i];
    __syncthreads();
    float av[NU];
    for (int a = 0; a < NU; a++) av[a] = A[a * 1024 + t];
    for (int b = 0; b < NU; b++) {
        float v = Csc[b * 1024 + t];
        for (int a = 0; a < NU; a++) v -= av[a] * sE[a * 20 + b];
        Ft[(NU + b) * 1024 + t] = f2b(v);
    }
}

// ============== fused main, v3: barrier-free DMA pipeline ======================
// 512 blocks x 256. Each wave owns 16 rows for BOTH phases (no cross-wave data).
// Phase A: x staged wave-privately via global_load_lds (2-deep, counted vmcnt,
// XOR-swizzled source so ds_read_b128 is ~conflict-free). F frags reg-prefetched
// 1 step ahead from L2. Phase B: r transposed through wave-private LDS, G/x from
// L2/L3. Zero __syncthreads in the whole kernel.
__global__ __launch_bounds__(256, 2) void k_main(
        const float* __restrict__ x, const unsigned short* __restrict__ Ft,
        const unsigned short* __restrict__ G, const float* __restrict__ s_ws,
        const float* __restrict__ b_ws, float* __restrict__ out) {
    __shared__ __align__(16) float xs[4][2][1024];         // 32 KiB: per-wave dbuf
    __shared__ __align__(16) unsigned short rl[4][16][72]; // 9 KiB: per-wave r tile

    const int T = threadIdx.x;
    const int wv = T >> 6, lane = T & 63;
    const int mc = lane & 15, quad = lane >> 4;
    const int m0 = blockIdx.x * 64 + wv * 16;

    // swizzle: LDS slot q' of row r holds source granule q = q' ^ r (involution)
#define STAGE(buf, t)                                                           \
    {                                                                           \
        _Pragma("unroll")                                                       \
        for (int i_ = 0; i_ < 4; i_++) {                                        \
            int r_ = i_ * 4 + (lane >> 4);                                      \
            int q_ = (lane & 15) ^ r_;                                          \
            gload_lds16(&x[(size_t)(m0 + r_) * 1024 + (t) * 64 + q_ * 4],       \
                        &xs[wv][buf][i_ * 256]);                                \
        }                                                                       \
    }

    // ---- Phase A: r(16x64) = x_rows(16x1024) . F(1024x64) ----
    f32x4 acc1[4];
#pragma unroll
    for (int i = 0; i < 4; i++) acc1[i] = (f32x4){0.f, 0.f, 0.f, 0.f};

    const unsigned short* fbase = Ft + (size_t)mc * 1024 + quad * 8;
    bf16x8 fA[8], fB[8];
#pragma unroll
    for (int j = 0; j < 8; j++)
        fA[j] = *(const bf16x8*)(fbase + (j & 3) * 16384 + (j >> 2) * 32);
    STAGE(0, 0);
    STAGE(1, 1);

#pragma unroll
    for (int t = 0; t < 16; t++) {
        // tile t staged? (leaves stage(t+1) in flight; never drains to 0 mid-loop)
        if (t < 15) asm volatile("s_waitcnt vmcnt(4)" ::: "memory");
        else        asm volatile("s_waitcnt vmcnt(0)" ::: "memory");
        __builtin_amdgcn_sched_barrier(0);

        const float* xb = &xs[wv][t & 1][0];
        bf16x8 af0, af1;
        {
            int q0 = quad * 2;
            f32x4 u0 = *(const f32x4*)&xb[mc * 64 + (q0 ^ mc) * 4];
            f32x4 u1 = *(const f32x4*)&xb[mc * 64 + ((q0 + 1) ^ mc) * 4];
#pragma unroll
            for (int j = 0; j < 4; j++) {
                af0[j] = (short)f2b(u0[j]);
                af0[j + 4] = (short)f2b(u1[j]);
            }
        }
        {
            int q0 = 8 + quad * 2;
            f32x4 u0 = *(const f32x4*)&xb[mc * 64 + (q0 ^ mc) * 4];
            f32x4 u1 = *(const f32x4*)&xb[mc * 64 + ((q0 + 1) ^ mc) * 4];
#pragma unroll
            for (int j = 0; j < 4; j++) {
                af1[j] = (short)f2b(u0[j]);
                af1[j + 4] = (short)f2b(u1[j]);
            }
        }
        // MFMA (compiler emits counted vmcnt for fA; stage(t+1) stays in flight)
        acc1[0] = __builtin_amdgcn_mfma_f32_16x16x32_bf16(af0, fA[0], acc1[0], 0, 0, 0);
        acc1[1] = __builtin_amdgcn_mfma_f32_16x16x32_bf16(af0, fA[1], acc1[1], 0, 0, 0);
        acc1[2] = __builtin_amdgcn_mfma_f32_16x16x32_bf16(af0, fA[2], acc1[2], 0, 0, 0);
        acc1[3] = __builtin_amdgcn_mfma_f32_16x16x32_bf16(af0, fA[3], acc1[3], 0, 0, 0);
        acc1[0] = __builtin_amdgcn_mfma_f32_16x16x32_bf16(af1, fA[4], acc1[0], 0, 0, 0);
        acc1[1] = __builtin_amdgcn_mfma_f32_16x16x32_bf16(af1, fA[5], acc1[1], 0, 0, 0);
        acc1[2] = __builtin_amdgcn_mfma_f32_16x16x32_bf16(af1, fA[6], acc1[2], 0, 0, 0);
        acc1[3] = __builtin_amdgcn_mfma_f32_16x16x32_bf16(af1, fA[7], acc1[3], 0, 0, 0);

        // prefetch F(t+1) (queue: [stage(t+1), F(t+1), stage(t+2)])
        if (t < 15) {
#pragma unroll
            for (int j = 0; j < 8; j++)
                fB[j] = *(const bf16x8*)(fbase + (j & 3) * 16384 + (t + 1) * 64 + (j >> 2) * 32);
        }
        __builtin_amdgcn_sched_barrier(0);  // pin stage below F-loads & MFMA consume
        if (t < 14) STAGE(t & 1, t + 2);
        if (t < 15) {
#pragma unroll
            for (int j = 0; j < 8; j++) fA[j] = fB[j];
        }
    }
#undef STAGE

    // ---- r -> wave-private LDS transpose (C-layout -> A-frag layout) ----
#pragma unroll
    for (int nt = 0; nt < 4; nt++)
#pragma unroll
        for (int rg = 0; rg < 4; rg++)
            rl[wv][quad * 4 + rg][nt * 16 + mc] = f2b(acc1[nt][rg]);
    // same-wave DS ordering; compiler inserts lgkm wait for the reads below
    bf16x8 pa0 = *(const bf16x8*)&rl[wv][mc][quad * 8];
    bf16x8 pa1 = *(const bf16x8*)&rl[wv][mc][32 + quad * 8];

    // ---- Phase B: out rows m0..m0+16, all 1024 cols, 64 n-frags ----
#pragma unroll 4
    for (int nf = 0; nf < 64; nf++) {
        const int col = nf * 16 + mc;
        const unsigned short* gp = &G[(size_t)col * 64 + quad * 8];
        bf16x8 g0 = *(const bf16x8*)(gp);
        bf16x8 g1 = *(const bf16x8*)(gp + 32);
        f32x4 a = (f32x4){0.f, 0.f, 0.f, 0.f};
        a = __builtin_amdgcn_mfma_f32_16x16x32_bf16(pa0, g0, a, 0, 0, 0);
        a = __builtin_amdgcn_mfma_f32_16x16x32_bf16(pa1, g1, a, 0, 0, 0);
        const float sv = s_ws[col], bv = b_ws[col];
        size_t base = (size_t)(m0 + quad * 4) * 1024 + col;
        out[base]        = x[base]        * sv - a[0] + bv;
        out[base + 1024] = x[base + 1024] * sv - a[1] + bv;
        out[base + 2048] = x[base + 2048] * sv - a[2] + bv;
        out[base + 3072] = x[base + 3072] * sv - a[3] + bv;
    }
}

extern "C" void kernel_launch(void* const* d_in, const int* in_sizes, int n_in,
                              void* d_out, int out_size, void* d_ws, size_t ws_size,
                              hipStream_t stream) {
    const float* x    = (const float*)d_in[0];
    const float* U    = (const float*)d_in[1];
    const float* p    = (const float*)d_in[2];
    const float* V    = (const float*)d_in[3];
    const float* bias = (const float*)d_in[4];

    char* ws = (char*)d_ws;
    unsigned short* Ft = (unsigned short*)ws;               // 131072 B
    unsigned short* G  = (unsigned short*)(ws + 131072);    // 131072 B
    float* s_ws        = (float*)(ws + 262144);             // 4096 B
    float* b_ws        = (float*)(ws + 266240);             // 4096 B
    float* GU          = (float*)(ws + 270336);             // 4096 B
    float* GV          = (float*)(ws + 274432);             // 4096 B
    float* A           = (float*)(ws + 278528);             // 81920 B
    float* Csc         = (float*)(ws + 360448);             // 81920 B
    float* E           = (float*)(ws + 442368);             // 4096 B
    float* out = (float*)d_out;

    hipLaunchKernelGGL(k_gram,  dim3(424), dim3(256), 0, stream, U, p, V, bias, GU, GV, s_ws, b_ws);
    hipLaunchKernelGGL(k_recur, dim3(4),   dim3(256), 0, stream, U, V, GU, GV, s_ws, A, Csc, Ft, G);
    hipLaunchKernelGGL(k_e,     dim3(400), dim3(256), 0, stream, U, Csc, E);
    hipLaunchKernelGGL(k_f2,    dim3(4),   dim3(256), 0, stream, A, Csc, E, Ft);
    hipLaunchKernelGGL(k_main,  dim3(512), dim3(256), 0, stream, x, Ft, G, s_ws, b_ws, out);
}

// Round 3
// 299.408 us; speedup vs baseline: 1.0500x; 1.0226x over previous
//
#include <hip/hip_runtime.h>
#include <hip/hip_bf16.h>

typedef __attribute__((ext_vector_type(8))) short bf16x8;
typedef __attribute__((ext_vector_type(4))) short bf16x4;
typedef __attribute__((ext_vector_type(4))) float f32x4;

#define NU 20

__device__ __forceinline__ float b2f(unsigned short u) {
    union { float f; unsigned v; } x; x.v = ((unsigned)u) << 16; return x.f;
}
__device__ __forceinline__ unsigned short f2b(float f) {
    union { float f; unsigned v; } x; x.f = f;
    unsigned r = x.v + 0x7FFF + ((x.v >> 16) & 1);
    return (unsigned short)(r >> 16);
}

__device__ __forceinline__ void gload_lds16(const void* g, void* l) {
    __builtin_amdgcn_global_load_lds(
        (const __attribute__((address_space(1))) void*)g,
        (__attribute__((address_space(3))) void*)l, 16, 0, 0);
}

// ================= build stage (parallelized: 424 + 4 + 400 + 4 blocks) =========
// L = H^U_0...H^U_19 = I - A B^T (B cols = U rows), R = H^V_19...H^V_0 = I - C D^T
// out = x*s - r.G^T + bias,  r = x.F,  F=[A | S C - A E], G=[S B | D], E=B^T S C

// blocks 0..209: GU pair, 210..419: GV pair, 420..423: sigma/bias chunk
__global__ __launch_bounds__(256) void k_gram(
        const float* __restrict__ U, const float* __restrict__ p,
        const float* __restrict__ V, const float* __restrict__ bias,
        float* __restrict__ GU, float* __restrict__ GV,
        float* __restrict__ s_ws, float* __restrict__ b_ws) {
    const int b = blockIdx.x, T = threadIdx.x;
    if (b >= 420) {
        int t = (b - 420) * 256 + T;
        float pv = p[t];
        s_ws[t] = 0.4f / (1.0f + __expf(-pv)) + 0.6f;
        b_ws[t] = bias[t];
        return;
    }
    const float* M = (b < 210) ? U : V;
    float* Gm = (b < 210) ? GU : GV;
    int i = (b < 210) ? b : b - 210;
    int k = 0;
    while ((k + 1) * (k + 2) / 2 <= i) k++;
    int j = i - k * (k + 1) / 2;
    f32x4 a4 = *(const f32x4*)&M[j * 1024 + T * 4];
    f32x4 b4 = *(const f32x4*)&M[k * 1024 + T * 4];
    float acc = a4[0] * b4[0] + a4[1] * b4[1] + a4[2] * b4[2] + a4[3] * b4[3];
    for (int off = 32; off; off >>= 1) acc += __shfl_down(acc, off, 64);
    __shared__ float part[4];
    if ((T & 63) == 0) part[T >> 6] = acc;
    __syncthreads();
    if (T == 0) {
        float s = part[0] + part[1] + part[2] + part[3];
        Gm[j * 20 + k] = s; Gm[k * 20 + j] = s;
    }
}

// 4 blocks x 256: per-dim WY recurrences. FULLY UNROLLED so a[]/c[] stay in
// registers (runtime-indexed arrays go to scratch: rule #20 — was ~scratch-bound).
__global__ __launch_bounds__(256) void k_recur(
        const float* __restrict__ U, const float* __restrict__ V,
        const float* __restrict__ GUg, const float* __restrict__ GVg,
        const float* __restrict__ s_ws,
        float* __restrict__ A, float* __restrict__ Csc,
        unsigned short* __restrict__ Ft, unsigned short* __restrict__ G) {
    __shared__ float sGU[400], sGV[400];
    const int T = threadIdx.x;
    const int t = blockIdx.x * 256 + T;
    for (int i = T; i < 400; i += 256) { sGU[i] = GUg[i]; sGV[i] = GVg[i]; }
    __syncthreads();
    float sig = s_ws[t];
    float a[NU], c[NU];
#pragma unroll
    for (int k = 0; k < NU; k++) {
        float w = U[k * 1024 + t];
#pragma unroll
        for (int j = 0; j < NU; j++) if (j < k) w -= a[j] * sGU[j * 20 + k];
        a[k] = (2.0f / sGU[k * 20 + k]) * w;
    }
#pragma unroll
    for (int k = NU - 1; k >= 0; k--) {
        float w = V[k * 1024 + t];
#pragma unroll
        for (int j = 0; j < NU; j++) if (j > k) w -= c[j] * sGV[j * 20 + k];
        c[k] = (2.0f / sGV[k * 20 + k]) * w;
    }
#pragma unroll
    for (int k = 0; k < NU; k++) { A[k * 1024 + t] = a[k]; Ft[k * 1024 + t] = f2b(a[k]); }
#pragma unroll
    for (int b = 0; b < NU; b++) Csc[b * 1024 + t] = sig * c[b];
    for (int k = 2 * NU; k < 64; k++) Ft[k * 1024 + t] = 0;
#pragma unroll
    for (int k = 0; k < NU; k++) G[t * 64 + k] = f2b(sig * U[k * 1024 + t]);
#pragma unroll
    for (int k = 0; k < NU; k++) G[t * 64 + NU + k] = f2b(V[k * 1024 + t]);
    for (int k = 2 * NU; k < 64; k++) G[t * 64 + k] = 0;
}

// 400 blocks: E[a][b] = dot(U row a, Csc row b)
__global__ __launch_bounds__(256) void k_e(
        const float* __restrict__ U, const float* __restrict__ Csc,
        float* __restrict__ E) {
    const int aa = blockIdx.x / 20, bb = blockIdx.x % 20;
    const int T = threadIdx.x;
    f32x4 a4 = *(const f32x4*)&U[aa * 1024 + T * 4];
    f32x4 b4 = *(const f32x4*)&Csc[bb * 1024 + T * 4];
    float acc = a4[0] * b4[0] + a4[1] * b4[1] + a4[2] * b4[2] + a4[3] * b4[3];
    for (int off = 32; off; off >>= 1) acc += __shfl_down(acc, off, 64);
    __shared__ float part[4];
    if ((T & 63) == 0) part[T >> 6] = acc;
    __syncthreads();
    if (T == 0) E[aa * 20 + bb] = part[0] + part[1] + part[2] + part[3];
}

// 4 blocks x 256: Ft rows 20..39 = (S C - A E) columns. Fully unrolled (scratch fix).
__global__ __launch_bounds__(256) void k_f2(
        const float* __restrict__ A, const float* __restrict__ Csc,
        const float* __restrict__ Eg, unsigned short* __restrict__ Ft) {
    __shared__ float sE[400];
    const int T = threadIdx.x;
    const int t = blockIdx.x * 256 + T;
    for (int i = T; i < 400; i += 256) sE[i] = Eg[i];
    __syncthreads();
    float av[NU];
#pragma unroll
    for (int a = 0; a < NU; a++) av[a] = A[a * 1024 + t];
#pragma unroll
    for (int b = 0; b < NU; b++) {
        float v = Csc[b * 1024 + t];
#pragma unroll
        for (int a = 0; a < NU; a++) v -= av[a] * sE[a * 20 + b];
        Ft[(NU + b) * 1024 + t] = f2b(v);
    }
}

// ============== fused main, v4: streaming-contiguous, TLP-first ================
// 2048 blocks x 256 (16 rows each), XCD-chunked swizzle. Phase A: K-tiles of 256;
// each gload_lds instr stages ONE fully-contiguous 1KB row chunk (row-padded LDS).
// Waves split the 64 r-columns (one 16x16 n-frag each). Phase B: operand-swapped
// MFMA (A=G, B=r) so each lane holds 4 consecutive out columns -> direct f32x4
// contiguous loads/stores, swept sequentially per wave. ~19KB LDS, 6 blocks/CU.
__global__ __launch_bounds__(256, 6) void k_main(
        const float* __restrict__ x, const unsigned short* __restrict__ Ft,
        const unsigned short* __restrict__ G, const float* __restrict__ s_ws,
        const float* __restrict__ b_ws, float* __restrict__ out) {
    __shared__ __align__(16) float xs[16][260];            // 16.6 KiB (row pad 16B)
    __shared__ __align__(16) unsigned short rl[16][72];    // 2.3 KiB

    const int T = threadIdx.x;
    const int wv = T >> 6, lane = T & 63;
    const int mc = lane & 15, quad = lane >> 4;
    // XCD-chunked swizzle: each XCD gets a contiguous 256-block (4096-row) span
    const int tile = (blockIdx.x & 7) * 256 + (blockIdx.x >> 3);
    const int m0 = tile * 16;

    // ---- Phase A: r(16x64) = x_rows(16x1024) . F(1024x64); wave wv owns n-frag wv ----
    f32x4 acc1 = (f32x4){0.f, 0.f, 0.f, 0.f};
    const unsigned short* fbase = Ft + (size_t)(wv * 16 + mc) * 1024 + quad * 8;

    for (int t = 0; t < 4; t++) {
        if (t) __syncthreads();          // all waves done reading xs tile t-1
        // stage: wave wv loads rows wv*4..+3; one instr = one 1KB contiguous row chunk
#pragma unroll
        for (int i = 0; i < 4; i++) {
            int row = wv * 4 + i;
            gload_lds16(&x[(size_t)(m0 + row) * 1024 + t * 256 + lane * 4], &xs[row][0]);
        }
        // F fragments for this K-tile (L2-hot after first blocks)
        bf16x8 ff[8];
#pragma unroll
        for (int kk = 0; kk < 8; kk++)
            ff[kk] = *(const bf16x8*)(fbase + t * 256 + kk * 32);
        __syncthreads();                 // implies vmcnt(0): stage complete
#pragma unroll
        for (int kk = 0; kk < 8; kk++) {
            f32x4 u0 = *(const f32x4*)&xs[mc][kk * 32 + quad * 8];
            f32x4 u1 = *(const f32x4*)&xs[mc][kk * 32 + quad * 8 + 4];
            bf16x8 af;
#pragma unroll
            for (int j = 0; j < 4; j++) {
                af[j]     = (short)f2b(u0[j]);
                af[j + 4] = (short)f2b(u1[j]);
            }
            acc1 = __builtin_amdgcn_mfma_f32_16x16x32_bf16(af, ff[kk], acc1, 0, 0, 0);
        }
    }

    // r -> LDS: lane holds r[m=quad*4+rg][n=wv*16+mc]
#pragma unroll
    for (int rg = 0; rg < 4; rg++)
        rl[quad * 4 + rg][wv * 16 + mc] = f2b(acc1[rg]);
    __syncthreads();

    // r as MFMA B-operand: lane holds r[m=mc][k=quad*8..+7]
    bf16x8 pa0 = *(const bf16x8*)&rl[mc][quad * 8];
    bf16x8 pa1 = *(const bf16x8*)&rl[mc][32 + quad * 8];

    // ---- Phase B: out cols [wv*256, +256); swapped MFMA -> row-contiguous f32x4 IO ----
    const int C0 = wv * 256;
#pragma unroll 2
    for (int nf = 0; nf < 16; nf++) {
        const int col0 = C0 + nf * 16;
        const unsigned short* gp = &G[(size_t)(col0 + mc) * 64 + quad * 8];
        bf16x8 g0 = *(const bf16x8*)(gp);
        bf16x8 g1 = *(const bf16x8*)(gp + 32);
        f32x4 a = (f32x4){0.f, 0.f, 0.f, 0.f};
        a = __builtin_amdgcn_mfma_f32_16x16x32_bf16(g0, pa0, a, 0, 0, 0);
        a = __builtin_amdgcn_mfma_f32_16x16x32_bf16(g1, pa1, a, 0, 0, 0);
        // lane (mc,quad) now holds out[m0+mc][col0+quad*4 .. +3]
        const int cc = col0 + quad * 4;
        f32x4 sv = *(const f32x4*)&s_ws[cc];
        f32x4 bv = *(const f32x4*)&b_ws[cc];
        size_t base = (size_t)(m0 + mc) * 1024 + cc;
        f32x4 xv = *(const f32x4*)&x[base];
        f32x4 o;
#pragma unroll
        for (int j = 0; j < 4; j++) o[j] = xv[j] * sv[j] - a[j] + bv[j];
        *(f32x4*)&out[base] = o;
    }
}

extern "C" void kernel_launch(void* const* d_in, const int* in_sizes, int n_in,
                              void* d_out, int out_size, void* d_ws, size_t ws_size,
                              hipStream_t stream) {
    const float* x    = (const float*)d_in[0];
    const float* U    = (const float*)d_in[1];
    const float* p    = (const float*)d_in[2];
    const float* V    = (const float*)d_in[3];
    const float* bias = (const float*)d_in[4];

    char* ws = (char*)d_ws;
    unsigned short* Ft = (unsigned short*)ws;               // 131072 B
    unsigned short* G  = (unsigned short*)(ws + 131072);    // 131072 B
    float* s_ws        = (float*)(ws + 262144);             // 4096 B
    float* b_ws        = (float*)(ws + 266240);             // 4096 B
    float* GU          = (float*)(ws + 270336);             // 4096 B
    float* GV          = (float*)(ws + 274432);             // 4096 B
    float* A           = (float*)(ws + 278528);             // 81920 B
    float* Csc         = (float*)(ws + 360448);             // 81920 B
    float* E           = (float*)(ws + 442368);             // 4096 B
    float* out = (float*)d_out;

    hipLaunchKernelGGL(k_gram,  dim3(424),  dim3(256), 0, stream, U, p, V, bias, GU, GV, s_ws, b_ws);
    hipLaunchKernelGGL(k_recur, dim3(4),    dim3(256), 0, stream, U, V, GU, GV, s_ws, A, Csc, Ft, G);
    hipLaunchKernelGGL(k_e,     dim3(400),  dim3(256), 0, stream, U, Csc, E);
    hipLaunchKernelGGL(k_f2,    dim3(4),    dim3(256), 0, stream, A, Csc, E, Ft);
    hipLaunchKernelGGL(k_main,  dim3(2048), dim3(256), 0, stream, x, Ft, G, s_ws, b_ws, out);
}